// Round 1
// baseline (43.990 us; speedup 1.0000x reference)
//
#include <hip/hip_runtime.h>

#define E 128
#define Fb 32
#define TSTRIDE 132  // padded LDS row stride (words); banks = (4*rj + rk) & 31

// ---------------- Kernel 1: data-independent rank-pair table ----------------
// T[a,c] = sum_u 1/((|u-a|+1)(|u-c|+1)) - S(a)*S(c)/(E-1)
__global__ void spearman_table(float* __restrict__ table) {
    int a = blockIdx.x;
    int c = threadIdx.x;
    float sa = 0.f, sc = 0.f, g = 0.f;
    for (int u = 0; u < E; ++u) {
        float wa = 1.0f / (float)(abs(u - a) + 1);
        float wc = 1.0f / (float)(abs(u - c) + 1);
        sa += wa;
        sc += wc;
        g += wa * wc;
    }
    table[a * E + c] = g - sa * sc * (1.0f / (float)(E - 1));
}

// ---------------- Kernel 2: stable ranks along electrode axis ----------------
// rank[i] = #{j: x[j] < x[i]} + #{j < i: x[j] == x[i]}  (== argsort(argsort(x)))
__global__ void spearman_ranks(const float* __restrict__ de,
                               unsigned char* __restrict__ ranks) {
    int bf = blockIdx.x;           // b*32 + f
    int b = bf >> 5, f = bf & 31;
    __shared__ float xs[E];
    int e = threadIdx.x;
    float v = de[(b * E + e) * Fb + f];
    xs[e] = v;
    __syncthreads();
    int cnt = 0;
#pragma unroll 8
    for (int j = 0; j < E; ++j) {
        float xj = xs[j];
        cnt += (int)(xj < v) + (int)((xj == v) & (j < e));
    }
    ranks[bf * E + e] = (unsigned char)cnt;
}

// ---------------- Kernel 3: out[b,j,k] = mean_f T[rj, rk] --------------------
// grid: 4 blocks per batch (32 output rows each), 256 threads.
// thread: k = tid&127 fixed column; jhalf = tid>>7 selects 16 of the 32 rows.
// rk[f] per-thread in VGPRs; row ranks in 16 wave-registers, broadcast via
// v_readlane (keeps the LDS pipe for gathers only).
__global__ __launch_bounds__(256, 2) void spearman_acc(
        const unsigned char* __restrict__ ranks,
        const float* __restrict__ table,
        float* __restrict__ out) {
    __shared__ __align__(16) float tbl[E * TSTRIDE];
    const int tid = threadIdx.x;
    const int b = blockIdx.x >> 2;
    const int q = blockIdx.x & 3;
    const int j0 = q * 32;

    // stage 64KB table into LDS at padded stride
    const float4* t4 = (const float4*)table;
#pragma unroll
    for (int i = 0; i < 16; ++i) {
        int idx = tid + i * 256;          // 0..4095 float4s
        float4 v = t4[idx];
        int a = idx >> 5;                 // 32 float4 per row
        int c4 = (idx & 31) << 2;
        *(float4*)&tbl[a * TSTRIDE + c4] = v;
    }

    const int k = tid & 127;
    const int jhalf = tid >> 7;           // uniform per wave
    const int lane = tid & 63;
    const unsigned char* rb = ranks + b * (Fb * E);

    // own-column ranks, one per freq band
    int rk[Fb];
#pragma unroll
    for (int f = 0; f < Fb; ++f) rk[f] = (int)rb[f * E + k];

    // wave-register copy of this block's 32 row-ranks x 32 bands:
    // reg rp, lane l  <->  (f = rp*2 + (l>>5), jloc = l&31)
    int rjreg[16];
#pragma unroll
    for (int rp = 0; rp < 16; ++rp) {
        int fl = rp * 2 + (lane >> 5);
        int jl = lane & 31;
        rjreg[rp] = (int)rb[fl * E + j0 + jl];
    }

    __syncthreads();

    float* ob = out + b * (E * E) + (j0 + jhalf * 16) * E + k;
    for (int r = 0; r < 16; ++r) {
        const int jloc = jhalf * 16 + r;  // uniform per wave
        const int laneA = jloc;           // f even
        const int laneB = jloc + 32;      // f odd
        float a0 = 0.f, a1 = 0.f, a2 = 0.f, a3 = 0.f;
#pragma unroll
        for (int f = 0; f < Fb; f += 4) {
            int rj0 = __builtin_amdgcn_readlane(rjreg[(f + 0) >> 1], laneA);
            int rj1 = __builtin_amdgcn_readlane(rjreg[(f + 1) >> 1], laneB);
            int rj2 = __builtin_amdgcn_readlane(rjreg[(f + 2) >> 1], laneA);
            int rj3 = __builtin_amdgcn_readlane(rjreg[(f + 3) >> 1], laneB);
            a0 += tbl[rj0 * TSTRIDE + rk[f + 0]];
            a1 += tbl[rj1 * TSTRIDE + rk[f + 1]];
            a2 += tbl[rj2 * TSTRIDE + rk[f + 2]];
            a3 += tbl[rj3 * TSTRIDE + rk[f + 3]];
        }
        ob[r * E] = (a0 + a1 + a2 + a3) * (1.0f / (float)Fb);
    }
}

extern "C" void kernel_launch(void* const* d_in, const int* in_sizes, int n_in,
                              void* d_out, int out_size, void* d_ws, size_t ws_size,
                              hipStream_t stream) {
    const float* de = (const float*)d_in[0];     // [128,128,32] f32
    float* out = (float*)d_out;                  // [128,128,128] f32

    const int B = 128;
    unsigned char* ranks = (unsigned char*)d_ws;                   // B*F*E = 512KB
    float* table = (float*)((char*)d_ws + (size_t)B * Fb * E);     // 64KB, 16B-aligned

    spearman_table<<<E, E, 0, stream>>>(table);
    spearman_ranks<<<B * Fb, E, 0, stream>>>(de, ranks);
    spearman_acc<<<B * 4, 256, 0, stream>>>(ranks, table, out);
}

// Round 2
// 41.831 us; speedup vs baseline: 1.0516x; 1.0516x over previous
//
#include <hip/hip_runtime.h>

#define E 128
#define Fb 32
#define TSH 136  // LDS row stride in halfwords (272B = 17*16B, keeps uint4 stores aligned)

__device__ inline float bf2f(unsigned short u) {
    union { unsigned int i; float f; } x;
    x.i = ((unsigned int)u) << 16;
    return x.f;
}

// ---------------- Kernel 1: data-independent rank-pair table (bf16) ----------
// T[a,c] = sum_u 1/((|u-a|+1)(|u-c|+1)) - S(a)*S(c)/(E-1)
__global__ void spearman_table(unsigned short* __restrict__ table) {
    int a = blockIdx.x;
    int c = threadIdx.x;
    float sa = 0.f, sc = 0.f, g = 0.f;
    for (int u = 0; u < E; ++u) {
        float wa = 1.0f / (float)(abs(u - a) + 1);
        float wc = 1.0f / (float)(abs(u - c) + 1);
        sa += wa;
        sc += wc;
        g += wa * wc;
    }
    float t = g - sa * sc * (1.0f / (float)(E - 1));
    // round-to-nearest-even bf16
    union { float f; unsigned int i; } x;
    x.f = t;
    unsigned int r = (x.i + 0x7FFFu + ((x.i >> 16) & 1u)) >> 16;
    table[a * E + c] = (unsigned short)r;
}

// ---------------- Kernel 2: stable ranks along electrode axis ----------------
// rank[i] = #{j: x[j] < x[i]} + #{j < i: x[j] == x[i]}  (== argsort(argsort(x)))
__global__ void spearman_ranks(const float* __restrict__ de,
                               unsigned char* __restrict__ ranks) {
    int bf = blockIdx.x;           // b*32 + f
    int b = bf >> 5, f = bf & 31;
    __shared__ __align__(16) float xs[E];
    int e = threadIdx.x;
    float v = de[(b * E + e) * Fb + f];
    xs[e] = v;
    __syncthreads();
    int cnt = 0;
    const float4* x4 = (const float4*)xs;
#pragma unroll 8
    for (int j4 = 0; j4 < E / 4; ++j4) {
        float4 q = x4[j4];
        int j = j4 * 4;
        cnt += (int)(q.x < v) + (int)((q.x == v) & (j + 0 < e));
        cnt += (int)(q.y < v) + (int)((q.y == v) & (j + 1 < e));
        cnt += (int)(q.z < v) + (int)((q.z == v) & (j + 2 < e));
        cnt += (int)(q.w < v) + (int)((q.w == v) & (j + 3 < e));
    }
    ranks[bf * E + e] = (unsigned char)cnt;
}

// ---------------- Kernel 3: out[b,j,k] = mean_f T[rj, rk] --------------------
// 8 blocks per batch (16 output rows each), 256 threads, bf16 table in LDS
// (34.8 KB -> 4 blocks/CU = 16 waves/CU). 8 accumulators -> 8 outstanding
// ds_reads per wait batch. Row ranks broadcast via v_readlane (off LDS pipe).
__global__ __launch_bounds__(256, 4) void spearman_acc(
        const unsigned char* __restrict__ ranks,
        const unsigned short* __restrict__ table,
        float* __restrict__ out) {
    __shared__ __align__(16) unsigned short tbl[E * TSH];
    const int tid = threadIdx.x;
    const int b = blockIdx.x >> 3;
    const int q = blockIdx.x & 7;
    const int j0 = q * 16;

    // stage 32KB bf16 table into LDS at padded stride
    const uint4* t16 = (const uint4*)table;   // 2048 uint4, 16 per row
#pragma unroll
    for (int i = 0; i < 8; ++i) {
        int idx = tid + i * 256;
        uint4 v = t16[idx];
        int a = idx >> 4;            // row
        int c = (idx & 15) * 8;      // halfword offset in row
        *(uint4*)&tbl[a * TSH + c] = v;
    }

    const int k = tid & 127;
    const int jhalf = tid >> 7;           // uniform per wave
    const int lane = tid & 63;
    const unsigned char* rb = ranks + b * (Fb * E);

    // own-column ranks, one per freq band (coalesced: 64 consecutive bytes/wave)
    int rk[Fb];
#pragma unroll
    for (int f = 0; f < Fb; ++f) rk[f] = (int)rb[f * E + k];

    // wave-register copy of this block's 16 row-ranks x 32 bands:
    // reg rp, lane l  <->  (f = rp*4 + (l>>4), jloc = l&15)
    int rjreg[8];
#pragma unroll
    for (int rp = 0; rp < 8; ++rp) {
        int fl = rp * 4 + (lane >> 4);
        int jl = lane & 15;
        rjreg[rp] = (int)rb[fl * E + j0 + jl];
    }

    __syncthreads();

    float* ob = out + b * (E * E) + (j0 + jhalf * 8) * E + k;
    for (int r = 0; r < 8; ++r) {
        const int jloc = jhalf * 8 + r;   // uniform per wave
        float a0 = 0.f, a1 = 0.f, a2 = 0.f, a3 = 0.f;
        float a4 = 0.f, a5 = 0.f, a6 = 0.f, a7 = 0.f;
#pragma unroll
        for (int s = 0; s < 4; ++s) {
            const int f = s * 8;
            int rj0 = __builtin_amdgcn_readlane(rjreg[(f + 0) >> 2], ((f + 0) & 3) * 16 + jloc);
            int rj1 = __builtin_amdgcn_readlane(rjreg[(f + 1) >> 2], ((f + 1) & 3) * 16 + jloc);
            int rj2 = __builtin_amdgcn_readlane(rjreg[(f + 2) >> 2], ((f + 2) & 3) * 16 + jloc);
            int rj3 = __builtin_amdgcn_readlane(rjreg[(f + 3) >> 2], ((f + 3) & 3) * 16 + jloc);
            int rj4 = __builtin_amdgcn_readlane(rjreg[(f + 4) >> 2], ((f + 4) & 3) * 16 + jloc);
            int rj5 = __builtin_amdgcn_readlane(rjreg[(f + 5) >> 2], ((f + 5) & 3) * 16 + jloc);
            int rj6 = __builtin_amdgcn_readlane(rjreg[(f + 6) >> 2], ((f + 6) & 3) * 16 + jloc);
            int rj7 = __builtin_amdgcn_readlane(rjreg[(f + 7) >> 2], ((f + 7) & 3) * 16 + jloc);
            a0 += bf2f(tbl[rj0 * TSH + rk[f + 0]]);
            a1 += bf2f(tbl[rj1 * TSH + rk[f + 1]]);
            a2 += bf2f(tbl[rj2 * TSH + rk[f + 2]]);
            a3 += bf2f(tbl[rj3 * TSH + rk[f + 3]]);
            a4 += bf2f(tbl[rj4 * TSH + rk[f + 4]]);
            a5 += bf2f(tbl[rj5 * TSH + rk[f + 5]]);
            a6 += bf2f(tbl[rj6 * TSH + rk[f + 6]]);
            a7 += bf2f(tbl[rj7 * TSH + rk[f + 7]]);
        }
        ob[r * E] = (((a0 + a1) + (a2 + a3)) + ((a4 + a5) + (a6 + a7))) * (1.0f / (float)Fb);
    }
}

extern "C" void kernel_launch(void* const* d_in, const int* in_sizes, int n_in,
                              void* d_out, int out_size, void* d_ws, size_t ws_size,
                              hipStream_t stream) {
    const float* de = (const float*)d_in[0];     // [128,128,32] f32
    float* out = (float*)d_out;                  // [128,128,128] f32

    const int B = 128;
    unsigned char* ranks = (unsigned char*)d_ws;                        // 512KB
    unsigned short* table = (unsigned short*)((char*)d_ws + (size_t)B * Fb * E);  // 32KB

    spearman_table<<<E, E, 0, stream>>>(table);
    spearman_ranks<<<B * Fb, E, 0, stream>>>(de, ranks);
    spearman_acc<<<B * 8, 256, 0, stream>>>(ranks, table, out);
}

// Round 3
// 30.605 us; speedup vs baseline: 1.4374x; 1.3668x over previous
//
#include <hip/hip_runtime.h>

#define E 128
#define Fb 32
#define TSH 136  // LDS row stride in halfwords (272B = 17*16B, keeps uint4 stores aligned)

__device__ inline float bf2f(unsigned short u) {
    union { unsigned int i; float f; } x;
    x.i = ((unsigned int)u) << 16;
    return x.f;
}

// -------- Kernel 1 (fused): rank-pair table (bf16) + stable ranks ----------
// blocks [0,E):       T[a,c] = sum_u 1/((|u-a|+1)(|u-c|+1)) - S(a)S(c)/(E-1)
// blocks [E, E+B*Fb): rank[i] = #{j: x[j]<x[i]} + #{j<i: x[j]==x[i]}
__global__ void spearman_prep(const float* __restrict__ de,
                              unsigned char* __restrict__ ranks,
                              unsigned short* __restrict__ table) {
    if (blockIdx.x < E) {
        int a = blockIdx.x;
        int c = threadIdx.x;
        float sa = 0.f, sc = 0.f, g = 0.f;
        for (int u = 0; u < E; ++u) {
            float wa = 1.0f / (float)(abs(u - a) + 1);
            float wc = 1.0f / (float)(abs(u - c) + 1);
            sa += wa;
            sc += wc;
            g += wa * wc;
        }
        float t = g - sa * sc * (1.0f / (float)(E - 1));
        union { float f; unsigned int i; } x;
        x.f = t;
        unsigned int r = (x.i + 0x7FFFu + ((x.i >> 16) & 1u)) >> 16;  // RNE bf16
        table[a * E + c] = (unsigned short)r;
        return;
    }
    int bf = blockIdx.x - E;       // b*32 + f
    int b = bf >> 5, f = bf & 31;
    __shared__ __align__(16) float xs[E];
    int e = threadIdx.x;
    float v = de[(b * E + e) * Fb + f];
    xs[e] = v;
    __syncthreads();
    int cnt = 0;
    const float4* x4 = (const float4*)xs;
#pragma unroll 8
    for (int j4 = 0; j4 < E / 4; ++j4) {
        float4 q = x4[j4];
        int j = j4 * 4;
        cnt += (int)(q.x < v) + (int)((q.x == v) & (j + 0 < e));
        cnt += (int)(q.y < v) + (int)((q.y == v) & (j + 1 < e));
        cnt += (int)(q.z < v) + (int)((q.z == v) & (j + 2 < e));
        cnt += (int)(q.w < v) + (int)((q.w == v) & (j + 3 < e));
    }
    ranks[bf * E + e] = (unsigned char)cnt;
}

// ---------------- Kernel 2: out[b,j,k] = mean_f T[rj, rk] --------------------
// 8 blocks/batch (16 rows each), 256 threads, bf16 table in LDS (34.8 KB ->
// 4 blocks/CU). Wave w owns rows [j0+(w>>1)*8, +8) x cols [(w&1)*64, +64).
// Row ranks live in 4 wave-registers packed so every readlane uses a LITERAL
// lane index ((f&7)*8 | r) -> plain v_readlane_b32, no waterfall.
__global__ __launch_bounds__(256, 4) void spearman_acc(
        const unsigned char* __restrict__ ranks,
        const unsigned short* __restrict__ table,
        float* __restrict__ out) {
    __shared__ __align__(16) unsigned short tbl[E * TSH];
    const int tid = threadIdx.x;
    const int b = blockIdx.x >> 3;
    const int q = blockIdx.x & 7;

    // stage 32KB bf16 table into LDS at padded stride
    const uint4* t16 = (const uint4*)table;   // 2048 uint4, 16 per row
#pragma unroll
    for (int i = 0; i < 8; ++i) {
        int idx = tid + i * 256;
        uint4 v = t16[idx];
        int a = idx >> 4;            // row
        int c = (idx & 15) * 8;      // halfword offset in row
        *(uint4*)&tbl[a * TSH + c] = v;
    }

    const int wave = tid >> 6;            // 0..3
    const int lane = tid & 63;
    const int khalf = wave & 1;
    const int jh = wave >> 1;
    const int k = khalf * 64 + lane;
    const int j0 = q * 16 + jh * 8;       // this wave's 8 output rows
    const unsigned char* rb = ranks + b * (Fb * E);

    // own-column ranks, one per freq band (coalesced 64B/wave per f)
    int rk[Fb];
#pragma unroll
    for (int f = 0; f < Fb; ++f) rk[f] = (int)rb[f * E + k];

    // wave-register row ranks: reg rp, lane l <-> (f = rp*8 + (l>>3), j = j0 + (l&7))
    int rjreg[4];
#pragma unroll
    for (int rp = 0; rp < 4; ++rp) {
        int fl = rp * 8 + (lane >> 3);
        int jl = lane & 7;
        rjreg[rp] = (int)rb[fl * E + j0 + jl];
    }

    __syncthreads();

    float* ob = out + b * (E * E) + j0 * E + k;
#pragma unroll
    for (int r = 0; r < 8; ++r) {
        float a0 = 0.f, a1 = 0.f, a2 = 0.f, a3 = 0.f;
        float a4 = 0.f, a5 = 0.f, a6 = 0.f, a7 = 0.f;
#pragma unroll
        for (int s = 0; s < 4; ++s) {
            const int f = s * 8;
            int rj0 = __builtin_amdgcn_readlane(rjreg[(f + 0) >> 3], (((f + 0) & 7) << 3) | r);
            int rj1 = __builtin_amdgcn_readlane(rjreg[(f + 1) >> 3], (((f + 1) & 7) << 3) | r);
            int rj2 = __builtin_amdgcn_readlane(rjreg[(f + 2) >> 3], (((f + 2) & 7) << 3) | r);
            int rj3 = __builtin_amdgcn_readlane(rjreg[(f + 3) >> 3], (((f + 3) & 7) << 3) | r);
            int rj4 = __builtin_amdgcn_readlane(rjreg[(f + 4) >> 3], (((f + 4) & 7) << 3) | r);
            int rj5 = __builtin_amdgcn_readlane(rjreg[(f + 5) >> 3], (((f + 5) & 7) << 3) | r);
            int rj6 = __builtin_amdgcn_readlane(rjreg[(f + 6) >> 3], (((f + 6) & 7) << 3) | r);
            int rj7 = __builtin_amdgcn_readlane(rjreg[(f + 7) >> 3], (((f + 7) & 7) << 3) | r);
            a0 += bf2f(tbl[rj0 * TSH + rk[f + 0]]);
            a1 += bf2f(tbl[rj1 * TSH + rk[f + 1]]);
            a2 += bf2f(tbl[rj2 * TSH + rk[f + 2]]);
            a3 += bf2f(tbl[rj3 * TSH + rk[f + 3]]);
            a4 += bf2f(tbl[rj4 * TSH + rk[f + 4]]);
            a5 += bf2f(tbl[rj5 * TSH + rk[f + 5]]);
            a6 += bf2f(tbl[rj6 * TSH + rk[f + 6]]);
            a7 += bf2f(tbl[rj7 * TSH + rk[f + 7]]);
        }
        ob[r * E] = (((a0 + a1) + (a2 + a3)) + ((a4 + a5) + (a6 + a7))) * (1.0f / (float)Fb);
    }
}

extern "C" void kernel_launch(void* const* d_in, const int* in_sizes, int n_in,
                              void* d_out, int out_size, void* d_ws, size_t ws_size,
                              hipStream_t stream) {
    const float* de = (const float*)d_in[0];     // [128,128,32] f32
    float* out = (float*)d_out;                  // [128,128,128] f32

    const int B = 128;
    unsigned char* ranks = (unsigned char*)d_ws;                        // 512KB
    unsigned short* table = (unsigned short*)((char*)d_ws + (size_t)B * Fb * E);  // 32KB

    spearman_prep<<<E + B * Fb, E, 0, stream>>>(de, ranks, table);
    spearman_acc<<<B * 8, 256, 0, stream>>>(ranks, table, out);
}

// Round 4
// 29.890 us; speedup vs baseline: 1.4718x; 1.0239x over previous
//
#include <hip/hip_runtime.h>

#define E 128
#define Fb 32
#define TSH 136    // u16 stride per LDS table row (272 B)
#define ROWB 272   // table row byte stride

__device__ inline float bf2f(unsigned short u) {
    union { unsigned int i; float f; } x;
    x.i = ((unsigned int)u) << 16;
    return x.f;
}

// -------- Kernel 1 (fused): rank-pair table (bf16) + stable ranks ----------
// blocks [0,E):       T[a,c] = sum_u 1/((|u-a|+1)(|u-c|+1)) - S(a)S(c)/(E-1)
// blocks [E, E+B*Fb): rank[i] = #{j: x[j]<x[i]} + #{j<i: x[j]==x[i]}
// writes ranks[bf*E+e] (for row-rank loads) and ranksT[(b*E+e)*Fb+f]
// (transposed, for coalesced per-column rank loads in acc).
__global__ void spearman_prep(const float* __restrict__ de,
                              unsigned char* __restrict__ ranks,
                              unsigned char* __restrict__ ranksT,
                              unsigned short* __restrict__ table) {
    if (blockIdx.x < E) {
        int a = blockIdx.x;
        int c = threadIdx.x;
        float sa = 0.f, sc = 0.f, g = 0.f;
        for (int u = 0; u < E; ++u) {
            float wa = 1.0f / (float)(abs(u - a) + 1);
            float wc = 1.0f / (float)(abs(u - c) + 1);
            sa += wa;
            sc += wc;
            g += wa * wc;
        }
        float t = g - sa * sc * (1.0f / (float)(E - 1));
        union { float f; unsigned int i; } x;
        x.f = t;
        unsigned int r = (x.i + 0x7FFFu + ((x.i >> 16) & 1u)) >> 16;  // RNE bf16
        table[a * E + c] = (unsigned short)r;
        return;
    }
    int bf = blockIdx.x - E;       // b*32 + f
    int b = bf >> 5, f = bf & 31;
    __shared__ __align__(16) float xs[E];
    int e = threadIdx.x;
    float v = de[(b * E + e) * Fb + f];
    xs[e] = v;
    __syncthreads();
    int cnt = 0;
    const float4* x4 = (const float4*)xs;
#pragma unroll 8
    for (int j4 = 0; j4 < E / 4; ++j4) {
        float4 q = x4[j4];
        int j = j4 * 4;
        cnt += (int)(q.x < v) + (int)((q.x == v) & (j + 0 < e));
        cnt += (int)(q.y < v) + (int)((q.y == v) & (j + 1 < e));
        cnt += (int)(q.z < v) + (int)((q.z == v) & (j + 2 < e));
        cnt += (int)(q.w < v) + (int)((q.w == v) & (j + 3 < e));
    }
    ranks[bf * E + e] = (unsigned char)cnt;
    ranksT[(b * E + e) * Fb + f] = (unsigned char)cnt;
}

// ---------------- Kernel 2: out[b,j,k] = mean_f T[rj, rk], symmetric -------
// Per batch, 6 tiles of 32 rows x 64 cols covering {k>=j} at wave granularity:
//   t: (j0/32, k0/64) in (0,0)(0,1)(1,0)(1,1)(2,1)(3,1); tiles t=1,3 also
//   write their transpose into the uncomputed block rows 64-127 x cols 0-63.
// 768 blocks = exactly 3 blocks/CU (LDS 43.3KB). Wave = 1 row x 64 cols per
// gather -> uniform rj, single literal v_readlane, conflict-free ds_read_u16.
__global__ __launch_bounds__(256, 3) void spearman_acc(
        const unsigned char* __restrict__ ranks,
        const unsigned char* __restrict__ ranksT,
        const unsigned short* __restrict__ table,
        float* __restrict__ out) {
    __shared__ __align__(16) unsigned short tbl[E * TSH];  // 34816 B
    __shared__ __align__(16) float trans[64 * 33];         // 8448 B
    const int tid = threadIdx.x;
    const int b = blockIdx.x / 6;
    const int t = blockIdx.x % 6;
    const int ti  = (t < 4) ? (t >> 1) : (t - 2);   // {0,0,1,1,2,3}
    const int cb  = (t < 4) ? (t & 1) : 1;          // {0,1,0,1,1,1}
    const int mir = (t < 4) ? (t & 1) : 0;          // {0,1,0,1,0,0}
    const int j0 = ti * 32, k0 = cb * 64;

    const int wave = tid >> 6, lane = tid & 63;
    const int k = k0 + lane;                        // this thread's column
    const unsigned char* rb  = ranks  + b * (Fb * E);
    const unsigned char* rbT = ranksT + b * (Fb * E);

    // column ranks: 32 consecutive bytes per thread (coalesced uchar4 x8),
    // prescaled to table byte offsets
    int rk2[Fb];
#pragma unroll
    for (int f4 = 0; f4 < 8; ++f4) {
        uchar4 qv = *(const uchar4*)&rbT[k * Fb + f4 * 4];
        rk2[f4 * 4 + 0] = (int)qv.x * 2;
        rk2[f4 * 4 + 1] = (int)qv.y * 2;
        rk2[f4 * 4 + 2] = (int)qv.z * 2;
        rk2[f4 * 4 + 3] = (int)qv.w * 2;
    }

    // wave-register row ranks, prescaled by row byte stride:
    // reg rp, lane l <-> (f = rp*8 + (l>>3), row = j0 + wave + 4*(l&7))
    int rj272[4];
#pragma unroll
    for (int rp = 0; rp < 4; ++rp) {
        int fl = rp * 8 + (lane >> 3);
        int row = j0 + wave + 4 * (lane & 7);
        rj272[rp] = (int)rb[fl * E + row] * ROWB;
    }

    // stage 32KB bf16 table into LDS at padded stride
    const uint4* t16 = (const uint4*)table;   // 2048 uint4, 16 per row
#pragma unroll
    for (int i = 0; i < 8; ++i) {
        int idx = tid + i * 256;
        uint4 v = t16[idx];
        int a = idx >> 4;
        int c = (idx & 15) * 8;
        *(uint4*)&tbl[a * TSH + c] = v;
    }
    __syncthreads();

    float acc[8] = {0.f, 0.f, 0.f, 0.f, 0.f, 0.f, 0.f, 0.f};
#pragma unroll
    for (int f = 0; f < Fb; ++f) {
        const int rg = f >> 3, li = (f & 7) << 3;
        const int ck = rk2[f];
#pragma unroll
        for (int g = 0; g < 8; ++g) {
            int ro = __builtin_amdgcn_readlane(rj272[rg], li | g);
            acc[g] += bf2f(*(const unsigned short*)((const char*)tbl + ro + ck));
        }
    }

    const float s = 1.0f / (float)Fb;
    float* ob = out + b * (E * E);
#pragma unroll
    for (int g = 0; g < 8; ++g)
        ob[(j0 + wave + 4 * g) * E + k] = acc[g] * s;   // 256B coalesced

    if (mir) {
        // transpose through LDS, then coalesced stores of the mirror block
#pragma unroll
        for (int g = 0; g < 8; ++g)
            trans[lane * 33 + (wave + 4 * g)] = acc[g] * s;  // 2-way banks: free
        __syncthreads();
#pragma unroll
        for (int g = 0; g < 8; ++g) {
            int rr = (tid >> 5) + 8 * g;   // 0..63
            int cc = tid & 31;
            ob[(k0 + rr) * E + (j0 + cc)] = trans[rr * 33 + cc];
        }
    }
}

extern "C" void kernel_launch(void* const* d_in, const int* in_sizes, int n_in,
                              void* d_out, int out_size, void* d_ws, size_t ws_size,
                              hipStream_t stream) {
    const float* de = (const float*)d_in[0];     // [128,128,32] f32
    float* out = (float*)d_out;                  // [128,128,128] f32

    const int B = 128;
    unsigned char* ranks  = (unsigned char*)d_ws;                          // 512KB
    unsigned char* ranksT = (unsigned char*)d_ws + (size_t)B * Fb * E;     // 512KB
    unsigned short* table = (unsigned short*)((char*)d_ws + 2 * (size_t)B * Fb * E);  // 32KB

    spearman_prep<<<E + B * Fb, E, 0, stream>>>(de, ranks, ranksT, table);
    spearman_acc<<<B * 6, 256, 0, stream>>>(ranks, ranksT, table, out);
}